// Round 3
// baseline (298.035 us; speedup 1.0000x reference)
//
#include <hip/hip_runtime.h>
#include <hip/hip_bf16.h>

#define SEQ 2048
#define BHCOUNT 32
#define NROWS (BHCOUNT*SEQ)   /* 65536 rows of [64] */

typedef unsigned short u16;
typedef unsigned int u32;
using bf16x8 = __attribute__((ext_vector_type(8))) short;   // 8 bf16 = 4 VGPR
using f32x4  = __attribute__((ext_vector_type(4))) float;

__device__ __forceinline__ float bf2f(u16 h) {
    return __uint_as_float(((u32)h) << 16);
}
__device__ __forceinline__ u16 f2bf(float f) {
    u32 u = __float_as_uint(f);
    u32 r = (u + 0x7FFFu + ((u >> 16) & 1u)) >> 16;
    return (u16)r;
}

// ---------------------------------------------------------------------------
// Kernel 1: QKV projection.  x[65536][64] fp32 ->
//   Q bf16 [65536][64]  (pre-scaled by 0.125*log2e for exp2-domain softmax)
//   K bf16 [65536][64]
//   Vt bf16 [32 bh][64 d][2048 s]   (transposed per head for PV B-fragments)
// ---------------------------------------------------------------------------
__global__ __launch_bounds__(256) void qkv_kernel(
    const float* __restrict__ x,
    const float* __restrict__ wq, const float* __restrict__ bq,
    const float* __restrict__ wk, const float* __restrict__ bk,
    const float* __restrict__ wv, const float* __restrict__ bv,
    u16* __restrict__ Q, u16* __restrict__ K, u16* __restrict__ Vt)
{
    __shared__ float wqs[64*68], wks[64*68], wvs[64*68];
    __shared__ float xs[64*64];
    __shared__ float bqs[64], bks[64], bvs[64];
    const int t = threadIdx.x;

    for (int i = t*4; i < 4096; i += 1024) {
        int r = i >> 6, c = i & 63;
        *(float4*)&wqs[r*68+c] = *(const float4*)&wq[i];
        *(float4*)&wks[r*68+c] = *(const float4*)&wk[i];
        *(float4*)&wvs[r*68+c] = *(const float4*)&wv[i];
        *(float4*)&xs[i] = *(const float4*)&x[(size_t)blockIdx.x*4096 + i];
    }
    if (t < 64) { bqs[t] = bq[t]; bks[t] = bk[t]; bvs[t] = bv[t]; }
    __syncthreads();

    const int e = t & 63, wg = t >> 6;
    const int bh = blockIdx.x >> 5;          // 64 rows/block, 32 blocks per bh
    const int s0 = (blockIdx.x & 31) * 64;
    const float qscale = 0.125f * 1.44269504f;
    float va[16];

    #pragma unroll
    for (int g = 0; g < 2; ++g) {
        const int r0 = wg*16 + g*8;
        float aq[8], ak[8], av[8];
        #pragma unroll
        for (int i = 0; i < 8; ++i) { aq[i] = bqs[e]; ak[i] = bks[e]; av[i] = bvs[e]; }
        for (int ds = 0; ds < 16; ++ds) {
            float4 q4 = *(const float4*)&wqs[e*68 + ds*4];
            float4 k4 = *(const float4*)&wks[e*68 + ds*4];
            float4 v4 = *(const float4*)&wvs[e*68 + ds*4];
            #pragma unroll
            for (int i = 0; i < 8; ++i) {
                float4 xv = *(const float4*)&xs[(r0+i)*64 + ds*4];
                aq[i] += xv.x*q4.x + xv.y*q4.y + xv.z*q4.z + xv.w*q4.w;
                ak[i] += xv.x*k4.x + xv.y*k4.y + xv.z*k4.z + xv.w*k4.w;
                av[i] += xv.x*v4.x + xv.y*v4.y + xv.z*v4.z + xv.w*v4.w;
            }
        }
        #pragma unroll
        for (int i = 0; i < 8; ++i) {
            size_t row = (size_t)blockIdx.x*64 + r0 + i;
            Q[row*64 + e] = f2bf(aq[i]*qscale);
            K[row*64 + e] = f2bf(ak[i]);
            va[g*8+i] = av[i];
        }
    }

    // transpose V through xs (rotated layout keeps LDS banks conflict-free)
    __syncthreads();
    #pragma unroll
    for (int g = 0; g < 2; ++g)
        #pragma unroll
        for (int i = 0; i < 8; ++i) {
            int r = wg*16 + g*8 + i;
            xs[e*64 + ((r + e) & 63)] = va[g*8+i];
        }
    __syncthreads();
    const size_t vtbase = (size_t)bh * 64 * SEQ;
    for (int idx = t; idx < 4096; idx += 256) {
        int ee = idx >> 6, s = idx & 63;
        Vt[vtbase + (size_t)ee*SEQ + s0 + s] = f2bf(xs[ee*64 + ((s + ee) & 63)]);
    }
}

// ---------------------------------------------------------------------------
// Kernel 2: MFMA flash attention (bf16 in, fp32 acc).
// grid (32 qtiles, 32 bh); 4 waves, each wave owns 16 q-rows.
// kv-tile = 64.  K and Vt tiles staged in LDS with XOR-swizzled 16B slots
// (slot ^= row&7) so all ds_read_b128 fragment loads are conflict-free.
// A/B frags use identical lane->(row,k) fill => robust to k-permutation.
// C/D layout (HW-verified): col = lane&15, row = (lane>>4)*4 + reg.
// ---------------------------------------------------------------------------
__global__ __launch_bounds__(256) void attn_kernel(
    const u16* __restrict__ Q, const u16* __restrict__ K,
    const u16* __restrict__ Vt, u16* __restrict__ ctx)
{
    __shared__ u16 Ks [64*64];       // [kv][d], swizzled
    __shared__ u16 Vts[64*64];       // [d][kv], swizzled
    __shared__ u16 Ps [4*16*64];     // per-wave P tile [q][kv], swizzled

    const int t = threadIdx.x;
    const int wid = t >> 6, lane = t & 63;
    const int ln = lane & 15, g4 = lane >> 4;
    const int bh = blockIdx.y;
    const size_t base   = (size_t)bh * SEQ * 64;
    const size_t vtbase = (size_t)bh * 64 * SEQ;
    const int q0 = blockIdx.x * 64 + wid * 16;

    // Q fragments in registers: lane holds Q[q0+ln][kf*32 + g4*8 + j]
    bf16x8 qf[2];
    #pragma unroll
    for (int kf = 0; kf < 2; ++kf)
        qf[kf] = *(const bf16x8*)&Q[base + (size_t)(q0 + ln)*64 + kf*32 + g4*8];

    f32x4 oacc[4];
    float m[4], l[4];
    #pragma unroll
    for (int i = 0; i < 4; ++i) {
        oacc[i] = (f32x4){0.f, 0.f, 0.f, 0.f};
        m[i] = -1e30f; l[i] = 0.f;
    }

    for (int kt = 0; kt < 32; ++kt) {
        const int kv0 = kt * 64;
        __syncthreads();   // previous tile's LDS reads complete
        #pragma unroll
        for (int c = 0; c < 2; ++c) {
            int s = t + c*256;                 // 512 slots of 16B per tile
            int row = s >> 3, ks = s & 7;
            int phys = row*64 + ((ks ^ (row & 7)) << 3);
            *(uint4*)&Ks [phys] = *(const uint4*)&K [base  + (size_t)(kv0 + row)*64 + ks*8];
            *(uint4*)&Vts[phys] = *(const uint4*)&Vt[vtbase + (size_t)row*SEQ + kv0 + ks*8];
        }
        __syncthreads();

        // S = Q · K^T : 4 col-tiles of 16, K-frag row = kv col
        f32x4 sacc[4];
        #pragma unroll
        for (int nt = 0; nt < 4; ++nt) sacc[nt] = (f32x4){0.f, 0.f, 0.f, 0.f};
        #pragma unroll
        for (int nt = 0; nt < 4; ++nt) {
            #pragma unroll
            for (int kf = 0; kf < 2; ++kf) {
                int krow = nt*16 + ln;
                bf16x8 kfr = *(const bf16x8*)&Ks[krow*64 + (((kf*4 + g4) ^ (krow & 7)) << 3)];
                sacc[nt] = __builtin_amdgcn_mfma_f32_16x16x32_bf16(qf[kf], kfr, sacc[nt], 0, 0, 0);
            }
        }

        // online softmax (exp2 domain; Q pre-scaled). Row r state in reg r.
        #pragma unroll
        for (int r = 0; r < 4; ++r) {
            float a = fmaxf(fmaxf(sacc[0][r], sacc[1][r]), fmaxf(sacc[2][r], sacc[3][r]));
            a = fmaxf(a, __shfl_xor(a, 1));
            a = fmaxf(a, __shfl_xor(a, 2));
            a = fmaxf(a, __shfl_xor(a, 4));
            a = fmaxf(a, __shfl_xor(a, 8));
            float mn = fmaxf(m[r], a);
            float alpha = exp2f(m[r] - mn);
            m[r] = mn;
            float rs = 0.f;
            const int prow = g4*4 + r;
            #pragma unroll
            for (int nt = 0; nt < 4; ++nt) {
                float p = exp2f(sacc[nt][r] - mn);
                rs += p;
                int pcol = ln + 16*nt;
                Ps[wid*1024 + prow*64 + (((pcol >> 3) ^ (prow & 7)) << 3) + (pcol & 7)] = f2bf(p);
            }
            rs += __shfl_xor(rs, 1);
            rs += __shfl_xor(rs, 2);
            rs += __shfl_xor(rs, 4);
            rs += __shfl_xor(rs, 8);
            l[r] = l[r]*alpha + rs;
            #pragma unroll
            for (int dt = 0; dt < 4; ++dt) oacc[dt][r] *= alpha;
        }

        // O += P · V : P A-frags (per-wave LDS), V B-frags (Vts)
        bf16x8 pf[2];
        #pragma unroll
        for (int kf = 0; kf < 2; ++kf)
            pf[kf] = *(const bf16x8*)&Ps[wid*1024 + ln*64 + (((kf*4 + g4) ^ (ln & 7)) << 3)];
        #pragma unroll
        for (int dt = 0; dt < 4; ++dt) {
            #pragma unroll
            for (int kf = 0; kf < 2; ++kf) {
                int vrow = dt*16 + ln;
                bf16x8 vfr = *(const bf16x8*)&Vts[vrow*64 + (((kf*4 + g4) ^ (vrow & 7)) << 3)];
                oacc[dt] = __builtin_amdgcn_mfma_f32_16x16x32_bf16(pf[kf], vfr, oacc[dt], 0, 0, 0);
            }
        }
    }

    // epilogue: normalize and store ctx (row-major [row][64])
    #pragma unroll
    for (int r = 0; r < 4; ++r) {
        float inv = 1.f / l[r];
        size_t row = base + (size_t)(q0 + g4*4 + r)*64;
        #pragma unroll
        for (int dt = 0; dt < 4; ++dt)
            ctx[row + dt*16 + ln] = f2bf(oacc[dt][r] * inv);
    }
}

// ---------------------------------------------------------------------------
// Kernel 3: output projection. out[4096][1024] = ctx[4096][1024] @ wo^T + bo
// ---------------------------------------------------------------------------
__global__ __launch_bounds__(256) void oproj_kernel(
    const u16* __restrict__ ctx, const float* __restrict__ wo,
    const float* __restrict__ bo, float* __restrict__ out)
{
    __shared__ float As[64*68], Bs[64*68];
    const int t = threadIdx.x;
    const int tr = t >> 4, tc = t & 15;
    const int rb = blockIdx.x, cb = blockIdx.y;
    float acc[4][4];
    #pragma unroll
    for (int i = 0; i < 4; ++i)
        #pragma unroll
        for (int j = 0; j < 4; ++j) acc[i][j] = 0.f;

    for (int kt = 0; kt < 16; ++kt) {
        __syncthreads();
        for (int i = t*4; i < 4096; i += 1024) {
            int r = i >> 6, c = i & 63;
            ushort4 u = *(const ushort4*)&ctx[(size_t)(rb*64+r)*1024 + kt*64 + c];
            float4 f;
            f.x = bf2f(u.x); f.y = bf2f(u.y); f.z = bf2f(u.z); f.w = bf2f(u.w);
            *(float4*)&As[r*68+c] = f;
            *(float4*)&Bs[r*68+c] = *(const float4*)&wo[(size_t)(cb*64+r)*1024 + kt*64 + c];
        }
        __syncthreads();
        for (int ds = 0; ds < 16; ++ds) {
            float4 a4[4], b4[4];
            #pragma unroll
            for (int i = 0; i < 4; ++i) a4[i] = *(const float4*)&As[(4*tr+i)*68 + ds*4];
            #pragma unroll
            for (int j = 0; j < 4; ++j) b4[j] = *(const float4*)&Bs[(tc+16*j)*68 + ds*4];
            #pragma unroll
            for (int i = 0; i < 4; ++i)
                #pragma unroll
                for (int j = 0; j < 4; ++j)
                    acc[i][j] += a4[i].x*b4[j].x + a4[i].y*b4[j].y
                               + a4[i].z*b4[j].z + a4[i].w*b4[j].w;
        }
    }

    #pragma unroll
    for (int i = 0; i < 4; ++i)
        #pragma unroll
        for (int j = 0; j < 4; ++j) {
            int row = rb*64 + 4*tr + i;
            int col = cb*64 + tc + 16*j;
            out[(size_t)row*1024 + col] = acc[i][j] + bo[col];
        }
}

extern "C" void kernel_launch(void* const* d_in, const int* in_sizes, int n_in,
                              void* d_out, int out_size, void* d_ws, size_t ws_size,
                              hipStream_t stream) {
    (void)in_sizes; (void)n_in; (void)out_size; (void)ws_size;
    const float* x  = (const float*)d_in[0];
    const float* wq = (const float*)d_in[1];
    const float* bq = (const float*)d_in[2];
    const float* wk = (const float*)d_in[3];
    const float* bk = (const float*)d_in[4];
    const float* wv = (const float*)d_in[5];
    const float* bv = (const float*)d_in[6];
    const float* wo = (const float*)d_in[7];
    const float* bo = (const float*)d_in[8];
    float* out = (float*)d_out;

    // workspace: Q,K bf16 [65536][64]; Vt bf16 [32][64][2048]; ctx bf16 -> 32 MB
    u16* Qb  = (u16*)d_ws;
    u16* Kb  = Qb + (size_t)NROWS*64;
    u16* Vtb = Kb + (size_t)NROWS*64;
    u16* ctx = Vtb + (size_t)NROWS*64;

    qkv_kernel<<<dim3(NROWS/64), 256, 0, stream>>>(x, wq, bq, wk, bk, wv, bv, Qb, Kb, Vtb);
    attn_kernel<<<dim3(32, 32), 256, 0, stream>>>(Qb, Kb, Vtb, ctx);
    oproj_kernel<<<dim3(64, 16), 256, 0, stream>>>(ctx, wo, bo, out);
}

// Round 5
// 180.158 us; speedup vs baseline: 1.6543x; 1.6543x over previous
//
#include <hip/hip_runtime.h>
#include <hip/hip_bf16.h>

#define SEQ 2048
#define BHCOUNT 32
#define NROWS (BHCOUNT*SEQ)   /* 65536 rows of [64] */

typedef unsigned short u16;
typedef unsigned int u32;
using bf16x8 = __attribute__((ext_vector_type(8))) short;   // 8 bf16 = 4 VGPR
using f32x4  = __attribute__((ext_vector_type(4))) float;

__device__ __forceinline__ float bf2f(u16 h) {
    return __uint_as_float(((u32)h) << 16);
}
__device__ __forceinline__ u16 f2bf(float f) {
    u32 u = __float_as_uint(f);
    u32 r = (u + 0x7FFFu + ((u >> 16) & 1u)) >> 16;
    return (u16)r;
}

// ---------------------------------------------------------------------------
// Kernel 1: QKV projection.  x[65536][64] fp32 ->
//   Q bf16 [65536][64]  (pre-scaled by 0.125*log2e for exp2-domain softmax)
//   K bf16 [65536][64]
//   Vt bf16 [32 bh][64 d][2048 s]   (transposed per head for PV B-fragments)
// ---------------------------------------------------------------------------
__global__ __launch_bounds__(256) void qkv_kernel(
    const float* __restrict__ x,
    const float* __restrict__ wq, const float* __restrict__ bq,
    const float* __restrict__ wk, const float* __restrict__ bk,
    const float* __restrict__ wv, const float* __restrict__ bv,
    u16* __restrict__ Q, u16* __restrict__ K, u16* __restrict__ Vt)
{
    __shared__ float wqs[64*68], wks[64*68], wvs[64*68];
    __shared__ float xs[64*64];
    __shared__ float bqs[64], bks[64], bvs[64];
    const int t = threadIdx.x;

    for (int i = t*4; i < 4096; i += 1024) {
        int r = i >> 6, c = i & 63;
        *(float4*)&wqs[r*68+c] = *(const float4*)&wq[i];
        *(float4*)&wks[r*68+c] = *(const float4*)&wk[i];
        *(float4*)&wvs[r*68+c] = *(const float4*)&wv[i];
        *(float4*)&xs[i] = *(const float4*)&x[(size_t)blockIdx.x*4096 + i];
    }
    if (t < 64) { bqs[t] = bq[t]; bks[t] = bk[t]; bvs[t] = bv[t]; }
    __syncthreads();

    const int e = t & 63, wg = t >> 6;
    const int bh = blockIdx.x >> 5;          // 64 rows/block, 32 blocks per bh
    const int s0 = (blockIdx.x & 31) * 64;
    const float qscale = 0.125f * 1.44269504f;
    float va[16];

    #pragma unroll
    for (int g = 0; g < 2; ++g) {
        const int r0 = wg*16 + g*8;
        float aq[8], ak[8], av[8];
        #pragma unroll
        for (int i = 0; i < 8; ++i) { aq[i] = bqs[e]; ak[i] = bks[e]; av[i] = bvs[e]; }
        for (int ds = 0; ds < 16; ++ds) {
            float4 q4 = *(const float4*)&wqs[e*68 + ds*4];
            float4 k4 = *(const float4*)&wks[e*68 + ds*4];
            float4 v4 = *(const float4*)&wvs[e*68 + ds*4];
            #pragma unroll
            for (int i = 0; i < 8; ++i) {
                float4 xv = *(const float4*)&xs[(r0+i)*64 + ds*4];
                aq[i] += xv.x*q4.x + xv.y*q4.y + xv.z*q4.z + xv.w*q4.w;
                ak[i] += xv.x*k4.x + xv.y*k4.y + xv.z*k4.z + xv.w*k4.w;
                av[i] += xv.x*v4.x + xv.y*v4.y + xv.z*v4.z + xv.w*v4.w;
            }
        }
        #pragma unroll
        for (int i = 0; i < 8; ++i) {
            size_t row = (size_t)blockIdx.x*64 + r0 + i;
            Q[row*64 + e] = f2bf(aq[i]*qscale);
            K[row*64 + e] = f2bf(ak[i]);
            va[g*8+i] = av[i];
        }
    }

    // transpose V through xs (rotated layout keeps LDS banks conflict-free)
    __syncthreads();
    #pragma unroll
    for (int g = 0; g < 2; ++g)
        #pragma unroll
        for (int i = 0; i < 8; ++i) {
            int r = wg*16 + g*8 + i;
            xs[e*64 + ((r + e) & 63)] = va[g*8+i];
        }
    __syncthreads();
    const size_t vtbase = (size_t)bh * 64 * SEQ;
    for (int idx = t; idx < 4096; idx += 256) {
        int ee = idx >> 6, s = idx & 63;
        Vt[vtbase + (size_t)ee*SEQ + s0 + s] = f2bf(xs[ee*64 + ((s + ee) & 63)]);
    }
}

// ---------------------------------------------------------------------------
// Kernel 2: MFMA flash attention (bf16 in, fp32 acc).
// grid (32 qtiles, 32 bh); 4 waves, each wave owns 16 q-rows.
// kv-tile = 64.  K and Vt tiles staged in LDS with XOR-swizzled 16B slots
// (slot ^= row&7) so all ds_read_b128 fragment loads are conflict-free.
// A/B frags use identical lane->(row,k) fill => robust to k-permutation.
// C/D layout (HW-verified): col = lane&15, row = (lane>>4)*4 + reg.
// ---------------------------------------------------------------------------
__global__ __launch_bounds__(256) void attn_kernel(
    const u16* __restrict__ Q, const u16* __restrict__ K,
    const u16* __restrict__ Vt, u16* __restrict__ ctx)
{
    __shared__ u16 Ks [64*64];       // [kv][d], swizzled
    __shared__ u16 Vts[64*64];       // [d][kv], swizzled
    __shared__ u16 Ps [4*16*64];     // per-wave P tile [q][kv], swizzled

    const int t = threadIdx.x;
    const int wid = t >> 6, lane = t & 63;
    const int ln = lane & 15, g4 = lane >> 4;
    const int bh = blockIdx.y;
    const size_t base   = (size_t)bh * SEQ * 64;
    const size_t vtbase = (size_t)bh * 64 * SEQ;
    const int q0 = blockIdx.x * 64 + wid * 16;

    // Q fragments in registers: lane holds Q[q0+ln][kf*32 + g4*8 + j]
    bf16x8 qf[2];
    #pragma unroll
    for (int kf = 0; kf < 2; ++kf)
        qf[kf] = *(const bf16x8*)&Q[base + (size_t)(q0 + ln)*64 + kf*32 + g4*8];

    f32x4 oacc[4];
    float m[4], l[4];
    #pragma unroll
    for (int i = 0; i < 4; ++i) {
        oacc[i] = (f32x4){0.f, 0.f, 0.f, 0.f};
        m[i] = -1e30f; l[i] = 0.f;
    }

    for (int kt = 0; kt < 32; ++kt) {
        const int kv0 = kt * 64;
        __syncthreads();   // previous tile's LDS reads complete
        #pragma unroll
        for (int c = 0; c < 2; ++c) {
            int s = t + c*256;                 // 512 slots of 16B per tile
            int row = s >> 3, ks = s & 7;
            int phys = row*64 + ((ks ^ (row & 7)) << 3);
            *(uint4*)&Ks [phys] = *(const uint4*)&K [base  + (size_t)(kv0 + row)*64 + ks*8];
            *(uint4*)&Vts[phys] = *(const uint4*)&Vt[vtbase + (size_t)row*SEQ + kv0 + ks*8];
        }
        __syncthreads();

        // S = Q · K^T : 4 col-tiles of 16, K-frag row = kv col
        f32x4 sacc[4];
        #pragma unroll
        for (int nt = 0; nt < 4; ++nt) sacc[nt] = (f32x4){0.f, 0.f, 0.f, 0.f};
        #pragma unroll
        for (int nt = 0; nt < 4; ++nt) {
            #pragma unroll
            for (int kf = 0; kf < 2; ++kf) {
                int krow = nt*16 + ln;
                bf16x8 kfr = *(const bf16x8*)&Ks[krow*64 + (((kf*4 + g4) ^ (krow & 7)) << 3)];
                sacc[nt] = __builtin_amdgcn_mfma_f32_16x16x32_bf16(qf[kf], kfr, sacc[nt], 0, 0, 0);
            }
        }

        // online softmax (exp2 domain; Q pre-scaled). Row r state in reg r.
        #pragma unroll
        for (int r = 0; r < 4; ++r) {
            float a = fmaxf(fmaxf(sacc[0][r], sacc[1][r]), fmaxf(sacc[2][r], sacc[3][r]));
            a = fmaxf(a, __shfl_xor(a, 1));
            a = fmaxf(a, __shfl_xor(a, 2));
            a = fmaxf(a, __shfl_xor(a, 4));
            a = fmaxf(a, __shfl_xor(a, 8));
            float mn = fmaxf(m[r], a);
            float alpha = exp2f(m[r] - mn);
            m[r] = mn;
            float rs = 0.f;
            const int prow = g4*4 + r;
            #pragma unroll
            for (int nt = 0; nt < 4; ++nt) {
                float p = exp2f(sacc[nt][r] - mn);
                rs += p;
                int pcol = ln + 16*nt;
                Ps[wid*1024 + prow*64 + (((pcol >> 3) ^ (prow & 7)) << 3) + (pcol & 7)] = f2bf(p);
            }
            rs += __shfl_xor(rs, 1);
            rs += __shfl_xor(rs, 2);
            rs += __shfl_xor(rs, 4);
            rs += __shfl_xor(rs, 8);
            l[r] = l[r]*alpha + rs;
            #pragma unroll
            for (int dt = 0; dt < 4; ++dt) oacc[dt][r] *= alpha;
        }

        // O += P · V : P A-frags (per-wave LDS), V B-frags (Vts)
        bf16x8 pf[2];
        #pragma unroll
        for (int kf = 0; kf < 2; ++kf)
            pf[kf] = *(const bf16x8*)&Ps[wid*1024 + ln*64 + (((kf*4 + g4) ^ (ln & 7)) << 3)];
        #pragma unroll
        for (int dt = 0; dt < 4; ++dt) {
            #pragma unroll
            for (int kf = 0; kf < 2; ++kf) {
                int vrow = dt*16 + ln;
                bf16x8 vfr = *(const bf16x8*)&Vts[vrow*64 + (((kf*4 + g4) ^ (vrow & 7)) << 3)];
                oacc[dt] = __builtin_amdgcn_mfma_f32_16x16x32_bf16(pf[kf], vfr, oacc[dt], 0, 0, 0);
            }
        }
    }

    // epilogue: normalize and store ctx (row-major [row][64])
    #pragma unroll
    for (int r = 0; r < 4; ++r) {
        float inv = 1.f / l[r];
        size_t row = base + (size_t)(q0 + g4*4 + r)*64;
        #pragma unroll
        for (int dt = 0; dt < 4; ++dt)
            ctx[row + dt*16 + ln] = f2bf(oacc[dt][r] * inv);
    }
}

// ---------------------------------------------------------------------------
// Kernel 3a: convert wo fp32 [1024][1024] -> bf16 tiled
//   wob_t[cb][kt][row][k] = wo[cb*64+row][kt*64+k]   (tile = contiguous 4096)
// Runs after attn_kernel; output lives in the then-dead Q workspace region.
// ---------------------------------------------------------------------------
__global__ __launch_bounds__(256) void wconv_kernel(
    const float* __restrict__ wo, u16* __restrict__ wob_t)
{
    int g = blockIdx.x*256 + threadIdx.x;   // 131072 slots of 8 elems
    int tile = g >> 9, within = g & 511;
    int row = within >> 3, ks = within & 7;
    int cb = tile >> 4, kt = tile & 15;
    const float* src = &wo[(size_t)(cb*64 + row)*1024 + kt*64 + ks*8];
    float4 a = *(const float4*)src;
    float4 b = *(const float4*)(src + 4);
    u16 o[8];
    o[0]=f2bf(a.x); o[1]=f2bf(a.y); o[2]=f2bf(a.z); o[3]=f2bf(a.w);
    o[4]=f2bf(b.x); o[5]=f2bf(b.y); o[6]=f2bf(b.z); o[7]=f2bf(b.w);
    *(uint4*)&wob_t[(size_t)g*8] = *(uint4*)o;
}

// ---------------------------------------------------------------------------
// Kernel 3b: MFMA output projection.
//   out[m][n] = sum_k A[m][k] * wo[n][k] + bo[n],  M=4096, N=K=1024
// CRITICAL (round-4 lesson): the reference's ctx.reshape(B,S,HIDDEN) is a
// PLAIN flat reshape of the [b][h][s][d] buffer — so A is simply the ctx
// workspace reinterpreted as a flat row-major [4096][1024] matrix. Stage A
// rows with stride 1024 (8 x 16B contiguous slots per row). No head gather.
// Tile 128x64, 4 waves as 2x2, each wave 64x32 = 4x2 frags, 16 MFMA/k-step.
// Same swizzle + fragment recipe as attn_kernel (HW-verified).
// ---------------------------------------------------------------------------
__global__ __launch_bounds__(256) void oproj_kernel(
    const u16* __restrict__ ctx, const u16* __restrict__ wob_t,
    const float* __restrict__ bo, float* __restrict__ out)
{
    __shared__ u16 As[128*64];   // [m][k], swizzled
    __shared__ u16 Bs[64*64];    // [n][k], swizzled
    const int t = threadIdx.x;
    const int wid = t >> 6, lane = t & 63;
    const int ln = lane & 15, g4 = lane >> 4;
    const int wr = wid >> 1, wc = wid & 1;
    const int rb = blockIdx.x, cb = blockIdx.y;
    const int m0 = rb * 128;

    f32x4 acc[4][2];
    #pragma unroll
    for (int mf = 0; mf < 4; ++mf)
        #pragma unroll
        for (int nf = 0; nf < 2; ++nf)
            acc[mf][nf] = (f32x4){0.f, 0.f, 0.f, 0.f};

    for (int kt = 0; kt < 16; ++kt) {
        const u16* bsrc = &wob_t[(size_t)(cb*16 + kt) * 4096];
        __syncthreads();
        #pragma unroll
        for (int c = 0; c < 4; ++c) {
            int sA = t + c*256;                  // 1024 slots of 16B
            int row = sA >> 3, ks = sA & 7;
            *(uint4*)&As[row*64 + ((ks ^ (row & 7)) << 3)] =
                *(const uint4*)&ctx[(size_t)(m0 + row)*1024 + kt*64 + ks*8];
        }
        #pragma unroll
        for (int c = 0; c < 2; ++c) {
            int sB = t + c*256;                  // 512 slots of 16B
            int row = sB >> 3, ks = sB & 7;
            *(uint4*)&Bs[row*64 + ((ks ^ (row & 7)) << 3)] = *(const uint4*)&bsrc[sB*8];
        }
        __syncthreads();

        #pragma unroll
        for (int kf = 0; kf < 2; ++kf) {
            bf16x8 af[4], bfr[2];
            #pragma unroll
            for (int mf = 0; mf < 4; ++mf) {
                int arow = wr*64 + mf*16 + ln;
                af[mf] = *(const bf16x8*)&As[arow*64 + (((kf*4 + g4) ^ (arow & 7)) << 3)];
            }
            #pragma unroll
            for (int nf = 0; nf < 2; ++nf) {
                int brow = wc*32 + nf*16 + ln;
                bfr[nf] = *(const bf16x8*)&Bs[brow*64 + (((kf*4 + g4) ^ (brow & 7)) << 3)];
            }
            #pragma unroll
            for (int mf = 0; mf < 4; ++mf)
                #pragma unroll
                for (int nf = 0; nf < 2; ++nf)
                    acc[mf][nf] = __builtin_amdgcn_mfma_f32_16x16x32_bf16(af[mf], bfr[nf], acc[mf][nf], 0, 0, 0);
        }
    }

    #pragma unroll
    for (int mf = 0; mf < 4; ++mf)
        #pragma unroll
        for (int r = 0; r < 4; ++r) {
            int m = m0 + wr*64 + mf*16 + g4*4 + r;
            #pragma unroll
            for (int nf = 0; nf < 2; ++nf) {
                int col = cb*64 + wc*32 + nf*16 + ln;
                out[(size_t)m*1024 + col] = acc[mf][nf][r] + bo[col];
            }
        }
}

extern "C" void kernel_launch(void* const* d_in, const int* in_sizes, int n_in,
                              void* d_out, int out_size, void* d_ws, size_t ws_size,
                              hipStream_t stream) {
    (void)in_sizes; (void)n_in; (void)out_size; (void)ws_size;
    const float* x  = (const float*)d_in[0];
    const float* wq = (const float*)d_in[1];
    const float* bq = (const float*)d_in[2];
    const float* wk = (const float*)d_in[3];
    const float* bk = (const float*)d_in[4];
    const float* wv = (const float*)d_in[5];
    const float* bv = (const float*)d_in[6];
    const float* wo = (const float*)d_in[7];
    const float* bo = (const float*)d_in[8];
    float* out = (float*)d_out;

    // workspace: Q,K bf16 [65536][64]; Vt bf16 [32][64][2048]; ctx bf16 -> 32 MB
    // After attn_kernel, Q is dead -> its region hosts wob_t (2 MB of 8 MB).
    u16* Qb  = (u16*)d_ws;
    u16* Kb  = Qb + (size_t)NROWS*64;
    u16* Vtb = Kb + (size_t)NROWS*64;
    u16* ctx = Vtb + (size_t)NROWS*64;
    u16* wob_t = Qb;

    qkv_kernel<<<dim3(NROWS/64), 256, 0, stream>>>(x, wq, bq, wk, bk, wv, bv, Qb, Kb, Vtb);
    attn_kernel<<<dim3(32, 32), 256, 0, stream>>>(Qb, Kb, Vtb, ctx);
    wconv_kernel<<<dim3(512), 256, 0, stream>>>(wo, wob_t);
    oproj_kernel<<<dim3(32, 16), 256, 0, stream>>>(ctx, wob_t, bo, out);
}